// Round 1
// 386.019 us; speedup vs baseline: 1.0281x; 1.0281x over previous
//
#include <hip/hip_runtime.h>

// Problem constants
#define DM 4096   // d_model
#define DSZ 64    // d_state
#define NE 1024   // num evicted
#define SQ 2048   // seq len
#define NB 4      // batch

typedef __attribute__((ext_vector_type(8))) short bf16x8;
typedef __attribute__((ext_vector_type(4))) float f32x4;

__device__ __forceinline__ unsigned f2bf(float f) {
  union { float f; unsigned u; } v; v.f = f;
  return (v.u + 0x7fffu + ((v.u >> 16) & 1u)) >> 16;  // RNE fp32->bf16
}
__device__ __forceinline__ unsigned pack2(float lo, float hi) {
  return f2bf(lo) | (f2bf(hi) << 16);
}

__device__ __forceinline__ void load8(const float* __restrict__ ap, const float* __restrict__ bp,
                                      float4& a0, float4& a1, float4& a2, float4& a3,
                                      float4& b0, float4& b1, float4& b2, float4& b3) {
  a0 = *(const float4*)(ap);      a1 = *(const float4*)(ap + 4);
  a2 = *(const float4*)(ap + 8);  a3 = *(const float4*)(ap + 12);
  b0 = *(const float4*)(bp);      b1 = *(const float4*)(bp + 4);
  b2 = *(const float4*)(bp + 8);  b3 = *(const float4*)(bp + 12);
}

// ---------------------------------------------------------------------------
// K1: keys_part[ks][b][s][n] = partial over d-slice of evicted[b][n][:]·W_key[s][:]
// Grid 512 = B(4) x MT(16) x KS(8). Block 256 = 4 waves; 64x64 tile, BK=64.
// 1-ahead register prefetch + double-buffered LDS, ONE barrier per chunk.
// ---------------------------------------------------------------------------
__launch_bounds__(256)
__global__ void k_keys(const float* __restrict__ ev, const float* __restrict__ Wk,
                       float* __restrict__ keys_part) {
  __shared__ __align__(16) unsigned short As[2][64][72];
  __shared__ __align__(16) unsigned short Bs[2][64][72];
  const int bid = blockIdx.x;
  const int ks = bid & 7, mt = (bid >> 3) & 15, b = bid >> 7;
  const int n0 = mt * 64;
  const int t = threadIdx.x;
  const int w = t >> 6, m15 = t & 15, quad = (t & 63) >> 4;
  const int rowS = t >> 2, seg = (t & 3) * 16;

  f32x4 acc[4];
#pragma unroll
  for (int i = 0; i < 4; ++i) acc[i] = (f32x4){0.f, 0.f, 0.f, 0.f};

  const float* ap = ev + ((size_t)(b * NE + n0 + rowS)) * DM + ks * 512 + seg;
  const float* bp = Wk + (size_t)rowS * DM + ks * 512 + seg;

  float4 a0, a1, a2, a3, b0, b1, b2, b3;
  load8(ap, bp, a0, a1, a2, a3, b0, b1, b2, b3);
  int cur = 0;
  for (int ch = 0; ch < 8; ++ch) {
    *(uint4*)&As[cur][rowS][seg]     = (uint4){ pack2(a0.x,a0.y), pack2(a0.z,a0.w), pack2(a1.x,a1.y), pack2(a1.z,a1.w) };
    *(uint4*)&As[cur][rowS][seg + 8] = (uint4){ pack2(a2.x,a2.y), pack2(a2.z,a2.w), pack2(a3.x,a3.y), pack2(a3.z,a3.w) };
    *(uint4*)&Bs[cur][rowS][seg]     = (uint4){ pack2(b0.x,b0.y), pack2(b0.z,b0.w), pack2(b1.x,b1.y), pack2(b1.z,b1.w) };
    *(uint4*)&Bs[cur][rowS][seg + 8] = (uint4){ pack2(b2.x,b2.y), pack2(b2.z,b2.w), pack2(b3.x,b3.y), pack2(b3.z,b3.w) };
    __syncthreads();
    if (ch < 7) {  // issue next chunk's loads; latency hides under MFMA below
      ap += 64; bp += 64;
      load8(ap, bp, a0, a1, a2, a3, b0, b1, b2, b3);
    }
#pragma unroll
    for (int kk = 0; kk < 2; ++kk) {
      bf16x8 af = *(const bf16x8*)&As[cur][w * 16 + m15][kk * 32 + quad * 8];
#pragma unroll
      for (int tn = 0; tn < 4; ++tn) {
        bf16x8 bfr = *(const bf16x8*)&Bs[cur][tn * 16 + m15][kk * 32 + quad * 8];
        acc[tn] = __builtin_amdgcn_mfma_f32_16x16x32_bf16(af, bfr, acc[tn], 0, 0, 0);
      }
    }
    cur ^= 1;
  }
  // D frag: row (= token n) = quad*4+r, col (= s) = m15. 4 consecutive n -> float4 store.
  const int n = n0 + w * 16 + quad * 4;
#pragma unroll
  for (int tn = 0; tn < 4; ++tn) {
    const int s = tn * 16 + m15;
    float4 v = { acc[tn][0], acc[tn][1], acc[tn][2], acc[tn][3] };
    *(float4*)&keys_part[(size_t)ks * (NB * DSZ * NE) + ((size_t)(b * DSZ + s)) * NE + n] = v;
  }
}

// ---------------------------------------------------------------------------
// Ksum: summary[b][d] = mean_n evicted[b][n][d]. Grid 512 (n split 2-way, atomic).
// ---------------------------------------------------------------------------
__launch_bounds__(256)
__global__ void k_sum(const float* __restrict__ ev, float* __restrict__ summary) {
  __shared__ float red[256];
  const int bid = blockIdx.x;
  const int b = bid >> 7, rem = bid & 127;
  const int d0 = (rem >> 1) * 64, half = rem & 1;
  const int t = threadIdx.x;
  const int dl = t & 63, g = t >> 6;
  float acc = 0.f;
  const float* p = ev + ((size_t)(b * NE + half * 512 + g * 128)) * DM + d0 + dl;
  for (int i = 0; i < 128; ++i) { acc += *p; p += DM; }
  red[t] = acc;
  __syncthreads();
  if (t < 64) {
    float tot = red[t] + red[t + 64] + red[t + 128] + red[t + 192];
    atomicAdd(&summary[b * DM + d0 + t], tot * (1.f / 1024.f));
  }
}

// ---------------------------------------------------------------------------
// Kbeta: beta[b][s] = sigmoid(summary[b]·W_beta_w[s] + W_beta_b[s]). Grid 256.
// Wave shfl reduction (1 barrier instead of 16).
// ---------------------------------------------------------------------------
__launch_bounds__(256)
__global__ void k_beta(const float* __restrict__ summary, const float* __restrict__ Wbw,
                       const float* __restrict__ Wbb, float* __restrict__ beta) {
  __shared__ float wred[4];
  const int b = blockIdx.x >> 6, s = blockIdx.x & 63;
  const int t = threadIdx.x;
  const float* sp = summary + b * DM + t * 16;
  const float* wp = Wbw + (size_t)s * DM + t * 16;
  float acc = 0.f;
#pragma unroll
  for (int j = 0; j < 4; ++j) {
    float4 a  = *(const float4*)(sp + j * 4);
    float4 w4 = *(const float4*)(wp + j * 4);
    acc += a.x * w4.x + a.y * w4.y + a.z * w4.z + a.w * w4.w;
  }
#pragma unroll
  for (int off = 32; off > 0; off >>= 1) acc += __shfl_xor(acc, off);
  if ((t & 63) == 0) wred[t >> 6] = acc;
  __syncthreads();
  if (t == 0) {
    float x = wred[0] + wred[1] + wred[2] + wred[3] + Wbb[s];
    beta[b * DSZ + s] = 1.f / (1.f + expf(-x));
  }
}

// ---------------------------------------------------------------------------
// K2: softmax over n (sums the 8 K-split slabs), writes ww_t[b][s][n] in bf16.
// Grid 256 = one block per (b,s). Wave shfl reductions (2 barriers).
// ---------------------------------------------------------------------------
__launch_bounds__(256)
__global__ void k_softmax(const float* __restrict__ keys_part, unsigned short* __restrict__ ww_t) {
  __shared__ float wred[8];
  const int b = blockIdx.x >> 6, s = blockIdx.x & 63;
  const int t = threadIdx.x;
  const size_t base = ((size_t)(b * DSZ + s)) * NE + t * 4;
  float4 k = {0.f, 0.f, 0.f, 0.f};
#pragma unroll
  for (int sl = 0; sl < 8; ++sl) {
    float4 p = *(const float4*)&keys_part[(size_t)sl * (NB * DSZ * NE) + base];
    k.x += p.x; k.y += p.y; k.z += p.z; k.w += p.w;
  }
  float m = fmaxf(fmaxf(k.x, k.y), fmaxf(k.z, k.w));
#pragma unroll
  for (int off = 32; off > 0; off >>= 1) m = fmaxf(m, __shfl_xor(m, off));
  if ((t & 63) == 0) wred[t >> 6] = m;
  __syncthreads();
  const float M = fmaxf(fmaxf(wred[0], wred[1]), fmaxf(wred[2], wred[3]));
  float4 e = { expf(k.x - M), expf(k.y - M), expf(k.z - M), expf(k.w - M) };
  float ss = e.x + e.y + e.z + e.w;
#pragma unroll
  for (int off = 32; off > 0; off >>= 1) ss += __shfl_xor(ss, off);
  if ((t & 63) == 0) wred[4 + (t >> 6)] = ss;
  __syncthreads();
  const float inv = 1.f / (wred[4] + wred[5] + wred[6] + wred[7]);
  ushort4 o = { (unsigned short)f2bf(e.x * inv), (unsigned short)f2bf(e.y * inv),
                (unsigned short)f2bf(e.z * inv), (unsigned short)f2bf(e.w * inv) };
  *(ushort4*)&ww_t[((size_t)(b * DSZ + s)) * NE + t * 4] = o;
}

// ---------------------------------------------------------------------------
// K3: new_state^T[b][d][s] (bf16) = beta[b][s]*state[b][s][d] + sum_n ww[b][s][n]*ev[b][n][d]
// Grid 512 = B(4) x DT(128, 32-wide d tiles): 2 blocks/CU (was 1). Block 256.
// M=64(s) x N=32(d), BK=64(n). Prefetch + dbuf LDS, one barrier per chunk.
// ---------------------------------------------------------------------------
__launch_bounds__(256)
__global__ void k_update(const float* __restrict__ ev, const float* __restrict__ state,
                         const float* __restrict__ beta, const unsigned short* __restrict__ ww_t,
                         unsigned short* __restrict__ ns_t) {
  __shared__ __align__(16) unsigned short Aw[2][64][72];  // [s][n]
  __shared__ __align__(16) unsigned short Bt[2][32][72];  // [d][n]
  const int bid = blockIdx.x;
  const int dt = bid & 127, b = bid >> 7;
  const int d0 = dt * 32;
  const int t = threadIdx.x;
  const int w = t >> 6, m15 = t & 15, quad = (t & 63) >> 4;
  const int rowS = t >> 2, seg = (t & 3) * 16;
  const int npair = (t & 31) * 2, dquad = (t >> 5) * 4;

  f32x4 acc[2];
#pragma unroll
  for (int i = 0; i < 2; ++i) acc[i] = (f32x4){0.f, 0.f, 0.f, 0.f};

  const unsigned short* wp = ww_t + ((size_t)(b * DSZ + rowS)) * NE + seg;
  const float* ep = ev + ((size_t)(b * NE + npair)) * DM + d0 + dquad;

  uint4 wa = *(const uint4*)(wp), wb = *(const uint4*)(wp + 8);
  float4 r0 = *(const float4*)(ep), r1 = *(const float4*)(ep + DM);
  int cur = 0;
  for (int ch = 0; ch < 16; ++ch) {
    *(uint4*)&Aw[cur][rowS][seg]     = wa;
    *(uint4*)&Aw[cur][rowS][seg + 8] = wb;
    *(unsigned*)&Bt[cur][dquad + 0][npair] = pack2(r0.x, r1.x);
    *(unsigned*)&Bt[cur][dquad + 1][npair] = pack2(r0.y, r1.y);
    *(unsigned*)&Bt[cur][dquad + 2][npair] = pack2(r0.z, r1.z);
    *(unsigned*)&Bt[cur][dquad + 3][npair] = pack2(r0.w, r1.w);
    __syncthreads();
    if (ch < 15) {
      wp += 64; ep += (size_t)64 * DM;
      wa = *(const uint4*)(wp); wb = *(const uint4*)(wp + 8);
      r0 = *(const float4*)(ep); r1 = *(const float4*)(ep + DM);
    }
#pragma unroll
    for (int kk = 0; kk < 2; ++kk) {
      bf16x8 af = *(const bf16x8*)&Aw[cur][w * 16 + m15][kk * 32 + quad * 8];
#pragma unroll
      for (int tn = 0; tn < 2; ++tn) {
        bf16x8 bfr = *(const bf16x8*)&Bt[cur][tn * 16 + m15][kk * 32 + quad * 8];
        acc[tn] = __builtin_amdgcn_mfma_f32_16x16x32_bf16(af, bfr, acc[tn], 0, 0, 0);
      }
    }
    cur ^= 1;
  }
  // D frag: row = s = w*16+quad*4+r, col = d = d0+tn*16+m15. Store transposed [d][s].
  const int sbase = w * 16 + quad * 4;
#pragma unroll
  for (int tn = 0; tn < 2; ++tn) {
    const int d = d0 + tn * 16 + m15;
    float v[4];
#pragma unroll
    for (int r = 0; r < 4; ++r) {
      const int s = sbase + r;
      v[r] = beta[b * DSZ + s] * state[((size_t)(b * DSZ + s)) * DM + d] + acc[tn][r];
    }
    ushort4 o = { (unsigned short)f2bf(v[0]), (unsigned short)f2bf(v[1]),
                  (unsigned short)f2bf(v[2]), (unsigned short)f2bf(v[3]) };
    *(ushort4*)&ns_t[((size_t)(b * DM + d)) * DSZ + sbase] = o;
  }
}

// ---------------------------------------------------------------------------
// K4: q_part[ks][b][l][s] = partial current[b][l][:]·W_query[s][:]; fused gate
// logit partials into gate_acc (atomic, 4 contenders). Grid 512 = B x MT(32) x KS(4).
// Prefetch + dbuf LDS; gate_w slab hoisted to LDS once.
// ---------------------------------------------------------------------------
__launch_bounds__(256)
__global__ void k_q(const float* __restrict__ cur_, const float* __restrict__ Wq,
                    const float* __restrict__ gate_w,
                    float* __restrict__ q_part, float* __restrict__ gate_acc) {
  __shared__ __align__(16) unsigned short As[2][64][72];
  __shared__ __align__(16) unsigned short Bs[2][64][72];
  __shared__ float gwAll[1024];
  __shared__ float gred[256];
  const int bid = blockIdx.x;
  const int ks = bid & 3, mt = (bid >> 2) & 31, b = bid >> 7;
  const int l0 = mt * 64;
  const int t = threadIdx.x;
  const int w = t >> 6, m15 = t & 15, quad = (t & 63) >> 4;
  const int rowS = t >> 2, seg = (t & 3) * 16;

  f32x4 acc[4];
#pragma unroll
  for (int i = 0; i < 4; ++i) acc[i] = (f32x4){0.f, 0.f, 0.f, 0.f};
  float gpart = 0.f;

  // hoist the whole gate_w K-slab once (4 KB)
  *(float4*)&gwAll[t * 4] = *(const float4*)(gate_w + ks * 1024 + t * 4);

  const float* ap = cur_ + ((size_t)(b * SQ + l0 + rowS)) * DM + ks * 1024 + seg;
  const float* bp = Wq + (size_t)rowS * DM + ks * 1024 + seg;

  float4 a0, a1, a2, a3, b0, b1, b2, b3;
  load8(ap, bp, a0, a1, a2, a3, b0, b1, b2, b3);
  int cur = 0;
  for (int ch = 0; ch < 16; ++ch) {
    *(uint4*)&As[cur][rowS][seg]     = (uint4){ pack2(a0.x,a0.y), pack2(a0.z,a0.w), pack2(a1.x,a1.y), pack2(a1.z,a1.w) };
    *(uint4*)&As[cur][rowS][seg + 8] = (uint4){ pack2(a2.x,a2.y), pack2(a2.z,a2.w), pack2(a3.x,a3.y), pack2(a3.z,a3.w) };
    *(uint4*)&Bs[cur][rowS][seg]     = (uint4){ pack2(b0.x,b0.y), pack2(b0.z,b0.w), pack2(b1.x,b1.y), pack2(b1.z,b1.w) };
    *(uint4*)&Bs[cur][rowS][seg + 8] = (uint4){ pack2(b2.x,b2.y), pack2(b2.z,b2.w), pack2(b3.x,b3.y), pack2(b3.z,b3.w) };
    __syncthreads();
    {  // gate dot on the still-live a-regs (gwAll valid after first barrier)
      const float* g = &gwAll[ch * 64 + seg];
      gpart += a0.x*g[0]  + a0.y*g[1]  + a0.z*g[2]  + a0.w*g[3]
             + a1.x*g[4]  + a1.y*g[5]  + a1.z*g[6]  + a1.w*g[7]
             + a2.x*g[8]  + a2.y*g[9]  + a2.z*g[10] + a2.w*g[11]
             + a3.x*g[12] + a3.y*g[13] + a3.z*g[14] + a3.w*g[15];
    }
    if (ch < 15) {
      ap += 64; bp += 64;
      load8(ap, bp, a0, a1, a2, a3, b0, b1, b2, b3);
    }
#pragma unroll
    for (int kk = 0; kk < 2; ++kk) {
      bf16x8 af = *(const bf16x8*)&As[cur][w * 16 + m15][kk * 32 + quad * 8];
#pragma unroll
      for (int tn = 0; tn < 4; ++tn) {
        bf16x8 bfr = *(const bf16x8*)&Bs[cur][tn * 16 + m15][kk * 32 + quad * 8];
        acc[tn] = __builtin_amdgcn_mfma_f32_16x16x32_bf16(af, bfr, acc[tn], 0, 0, 0);
      }
    }
    cur ^= 1;
  }
  // q partial stores: row = l, col = s
  const int lrow = l0 + w * 16 + quad * 4;
#pragma unroll
  for (int tn = 0; tn < 4; ++tn) {
#pragma unroll
    for (int r = 0; r < 4; ++r) {
      q_part[(size_t)ks * (NB * SQ * DSZ) + ((size_t)(b * SQ + lrow + r)) * DSZ + tn * 16 + m15] =
          acc[tn][r];
    }
  }
  // gate partial reduce: row index = t>>2, partials at t = 4r..4r+3
  gred[t] = gpart;
  __syncthreads();
  if (t < 64) {
    float tot = gred[4 * t] + gred[4 * t + 1] + gred[4 * t + 2] + gred[4 * t + 3];
    atomicAdd(&gate_acc[b * SQ + l0 + t], tot);
  }
}

// ---------------------------------------------------------------------------
// Kqcvt: qbf[b][l][s] = bf16( sum of 4 q_part slabs ). Grid 512.
// ---------------------------------------------------------------------------
__launch_bounds__(256)
__global__ void k_qcvt(const float* __restrict__ q_part, unsigned short* __restrict__ qbf) {
  const int i = (blockIdx.x * 256 + threadIdx.x) * 4;
  const int SL = NB * SQ * DSZ;
  float4 v0 = *(const float4*)&q_part[i];
  float4 v1 = *(const float4*)&q_part[i + SL];
  float4 v2 = *(const float4*)&q_part[i + 2 * SL];
  float4 v3 = *(const float4*)&q_part[i + 3 * SL];
  float x = v0.x + v1.x + v2.x + v3.x;
  float y = v0.y + v1.y + v2.y + v3.y;
  float z = v0.z + v1.z + v2.z + v3.z;
  float u = v0.w + v1.w + v2.w + v3.w;
  ushort4 o = { (unsigned short)f2bf(x), (unsigned short)f2bf(y),
                (unsigned short)f2bf(z), (unsigned short)f2bf(u) };
  *(ushort4*)&qbf[i] = o;
}

// ---------------------------------------------------------------------------
// K5: out[b][l][d] = sigmoid(gate_acc[b][l]+gate_b) * sum_s q[l][s]*ns_t[d][s]
// Grid 8192 = B(4) x LT(32) x DT(64); block 256 = 4 waves; no LDS, frags from global.
// ---------------------------------------------------------------------------
__launch_bounds__(256)
__global__ void k_out(const unsigned short* __restrict__ qbf, const unsigned short* __restrict__ ns_t,
                      const float* __restrict__ gate_acc, const float* __restrict__ gate_b,
                      float* __restrict__ out) {
  const int bid = blockIdx.x;
  const int dt = bid & 63, lt = (bid >> 6) & 31, b = bid >> 11;
  const int d0 = dt * 64, l0 = lt * 64;
  const int t = threadIdx.x;
  const int w = t >> 6, m15 = t & 15, quad = (t & 63) >> 4;
  const int la = l0 + w * 16 + m15;
  f32x4 acc[4];
#pragma unroll
  for (int i = 0; i < 4; ++i) acc[i] = (f32x4){0.f, 0.f, 0.f, 0.f};
#pragma unroll
  for (int kk = 0; kk < 2; ++kk) {
    bf16x8 af = *(const bf16x8*)&qbf[((size_t)(b * SQ + la)) * DSZ + kk * 32 + quad * 8];
#pragma unroll
    for (int tn = 0; tn < 4; ++tn) {
      const int d = d0 + tn * 16 + m15;
      bf16x8 bfr = *(const bf16x8*)&ns_t[((size_t)(b * DM + d)) * DSZ + kk * 32 + quad * 8];
      acc[tn] = __builtin_amdgcn_mfma_f32_16x16x32_bf16(af, bfr, acc[tn], 0, 0, 0);
    }
  }
  const float gb = gate_b[0];
  const int lbase = l0 + w * 16 + quad * 4;
  float g[4];
#pragma unroll
  for (int r = 0; r < 4; ++r)
    g[r] = 1.f / (1.f + expf(-(gate_acc[b * SQ + lbase + r] + gb)));
#pragma unroll
  for (int tn = 0; tn < 4; ++tn) {
    const int d = d0 + tn * 16 + m15;
#pragma unroll
    for (int r = 0; r < 4; ++r)
      out[((size_t)(b * SQ + lbase + r)) * DM + d] = g[r] * acc[tn][r];
  }
}

// ---------------------------------------------------------------------------
extern "C" void kernel_launch(void* const* d_in, const int* in_sizes, int n_in,
                              void* d_out, int out_size, void* d_ws, size_t ws_size,
                              hipStream_t stream) {
  const float* state   = (const float*)d_in[0];
  const float* evicted = (const float*)d_in[1];
  const float* current = (const float*)d_in[2];
  const float* Wkey    = (const float*)d_in[3];
  const float* Wbw     = (const float*)d_in[4];
  const float* Wbb     = (const float*)d_in[5];
  const float* Wq      = (const float*)d_in[6];
  const float* gate_w  = (const float*)d_in[7];
  const float* gate_b  = (const float*)d_in[8];
  float* out = (float*)d_out;

  // workspace layout (≈19.6 MB total)
  float* f = (float*)d_ws;
  float* keys_part = f;                              // 8 * 262144 f  (8 MB)
  float* q_part    = keys_part + 8 * 262144;         // 4 * 524288 f  (8 MB)
  float* summary   = q_part + 4 * 524288;            // 16384 f
  float* gate_acc  = summary + 16384;                // 8192 f
  float* beta      = gate_acc + 8192;                // 256 f
  unsigned short* ww_t = (unsigned short*)(beta + 256);  // 262144 us (512 KB)
  unsigned short* qbf  = ww_t + 262144;                  // 524288 us (1 MB)
  unsigned short* ns_t = qbf + 524288;                   // 1048576 us (2 MB)

  // zero only the atomically-accumulated buffers (summary + gate_acc, contiguous)
  hipMemsetAsync(summary, 0, (16384 + 8192) * sizeof(float), stream);

  k_keys   <<<512,  256, 0, stream>>>(evicted, Wkey, keys_part);
  k_sum    <<<512,  256, 0, stream>>>(evicted, summary);
  k_beta   <<<256,  256, 0, stream>>>(summary, Wbw, Wbb, beta);
  k_softmax<<<256,  256, 0, stream>>>(keys_part, ww_t);
  k_update <<<512,  256, 0, stream>>>(evicted, state, beta, ww_t, ns_t);
  k_q      <<<512,  256, 0, stream>>>(current, Wq, gate_w, q_part, gate_acc);
  k_qcvt   <<<512,  256, 0, stream>>>(q_part, qbf);
  k_out    <<<8192, 256, 0, stream>>>(qbf, ns_t, gate_acc, gate_b, out);
}